// Round 1
// baseline (195.599 us; speedup 1.0000x reference)
//
#include <hip/hip_runtime.h>

// 2-layer tanh RNN, fused, f32.
// B=4096 chains, T=512 steps, H=20.
// Thread = (batch g in block, output j). Weights rows in VGPRs, h-state in
// LDS double buffer. Layer1 pipelined one step behind layer0 so both layers
// read the same h0[t-1] vector -> 1 barrier/iter.

#define Bsz 4096
#define Tn  512
#define Hn  20
#define GB  16                 // batches per block
#define NTHREADS (GB * Hn)     // 320 threads = 5 waves, 100% fill

__device__ __forceinline__ float tanh_fast(float v) {
    // exact identity tanh(v) = 1 - 2/(exp(2v)+1); __expf -> v_exp_f32,
    // rcp -> v_rcp_f32. Handles +-inf saturation correctly.
    float e = __expf(2.0f * v);
    return 1.0f - 2.0f * __builtin_amdgcn_rcpf(e + 1.0f);
}

__global__ __launch_bounds__(NTHREADS)
void rnn2_fused(const float* __restrict__ x,        // [B,T,1]
                const float* __restrict__ hidden,   // [2,B,H]
                const float* __restrict__ W_ih0,    // [H,1]
                const float* __restrict__ W_hh0,    // [H,H]
                const float* __restrict__ b_ih0,    // [H]
                const float* __restrict__ b_hh0,    // [H]
                const float* __restrict__ W_ih1,    // [H,H]
                const float* __restrict__ W_hh1,    // [H,H]
                const float* __restrict__ b_ih1,    // [H]
                const float* __restrict__ b_hh1,    // [H]
                const float* __restrict__ fc_w,     // [1,H]
                const float* __restrict__ fc_b,     // [1]
                float* __restrict__ out)            // [B] ++ [2,B,H] flat
{
    const int tid = threadIdx.x;
    const int g   = tid / Hn;          // batch within block
    const int j   = tid - g * Hn;      // output index 0..19
    const int b   = blockIdx.x * GB + g;

    // double-buffered hidden state, [buf][batch][h]; thread-linear writes
    __shared__ float h0s[2][GB][Hn];
    __shared__ float h1s[2][GB][Hn];

    // per-thread weight rows (rows are 80B => 16B-aligned float4 loads)
    float whh0[Hn], wih1[Hn], whh1[Hn];
    {
        const float4* p0 = (const float4*)(W_hh0 + j * Hn);
        const float4* p1 = (const float4*)(W_ih1 + j * Hn);
        const float4* p2 = (const float4*)(W_hh1 + j * Hn);
        #pragma unroll
        for (int r = 0; r < 5; ++r) {
            float4 v0 = p0[r], v1 = p1[r], v2 = p2[r];
            whh0[4*r+0] = v0.x; whh0[4*r+1] = v0.y; whh0[4*r+2] = v0.z; whh0[4*r+3] = v0.w;
            wih1[4*r+0] = v1.x; wih1[4*r+1] = v1.y; wih1[4*r+2] = v1.z; wih1[4*r+3] = v1.w;
            whh1[4*r+0] = v2.x; whh1[4*r+1] = v2.y; whh1[4*r+2] = v2.z; whh1[4*r+3] = v2.w;
        }
    }
    const float wih0  = W_ih0[j];
    const float bias0 = b_ih0[j] + b_hh0[j];
    const float bias1 = b_ih1[j] + b_hh1[j];

    // init state: h0 -> buf0; h1 -> buf0 AND buf1 (layer1's first read is
    // from buf1 at i=1, which i=0 does not write)
    h0s[0][g][j] = hidden[b * Hn + j];
    const float h1i = hidden[Bsz * Hn + b * Hn + j];
    h1s[0][g][j] = h1i;
    h1s[1][g][j] = h1i;

    const long xbase = (long)b * Tn;
    float xt = x[xbase];               // prefetch t=0
    __syncthreads();

    // iteration i: layer0 computes h0[i] (i<T), layer1 computes h1[i-1] (i>0).
    // reads buf p=i&1 (h0[i-1], h1[i-2]); writes buf p^1.
    #pragma unroll 2
    for (int i = 0; i <= Tn; ++i) {
        const int p = i & 1, q = p ^ 1;

        // prefetch next x (hides global latency under the FMAs)
        const int tnext = (i + 1 < Tn) ? (i + 1) : (Tn - 1);
        const float xn = x[xbase + tnext];

        // load h vectors (5x ds_read_b128 each; mostly broadcast within
        // each 20-thread group -> low bank pressure)
        float h0p[Hn], h1p[Hn];
        #pragma unroll
        for (int r = 0; r < 5; ++r) {
            *(float4*)&h0p[4*r] = *(const float4*)&h0s[p][g][4*r];
            *(float4*)&h1p[4*r] = *(const float4*)&h1s[p][g][4*r];
        }

        float acc0  = fmaf(xt, wih0, bias0);  // layer0 pre-activation
        float acc1  = bias1;                  // layer1 input-proj part
        float acc1b = 0.0f;                   // layer1 recurrent part
        #pragma unroll
        for (int k = 0; k < Hn; ++k) {
            acc0  = fmaf(whh0[k], h0p[k], acc0);
            acc1  = fmaf(wih1[k], h0p[k], acc1);
            acc1b = fmaf(whh1[k], h1p[k], acc1b);
        }

        if (i < Tn) h0s[q][g][j] = tanh_fast(acc0);
        if (i > 0)  h1s[q][g][j] = tanh_fast(acc1 + acc1b);

        xt = xn;
        __syncthreads();
    }

    // final states: h0[511] written at i=511 -> buf0; h1[511] at i=512 -> buf1
    const float h0f = h0s[0][g][j];
    const float h1f = h1s[1][g][j];
    out[Bsz + b * Hn + j]            = h0f;   // new_hidden[0]
    out[Bsz + Bsz * Hn + b * Hn + j] = h1f;   // new_hidden[1]

    if (j == 0) {  // fc head: one thread per batch
        float acc = fc_b[0];
        #pragma unroll
        for (int k = 0; k < Hn; ++k)
            acc = fmaf(fc_w[k], h1s[1][g][k], acc);
        out[b] = acc;
    }
}

extern "C" void kernel_launch(void* const* d_in, const int* in_sizes, int n_in,
                              void* d_out, int out_size, void* d_ws, size_t ws_size,
                              hipStream_t stream) {
    const float* x      = (const float*)d_in[0];
    const float* hidden = (const float*)d_in[1];
    const float* W_ih0  = (const float*)d_in[2];
    const float* W_hh0  = (const float*)d_in[3];
    const float* b_ih0  = (const float*)d_in[4];
    const float* b_hh0  = (const float*)d_in[5];
    const float* W_ih1  = (const float*)d_in[6];
    const float* W_hh1  = (const float*)d_in[7];
    const float* b_ih1  = (const float*)d_in[8];
    const float* b_hh1  = (const float*)d_in[9];
    const float* fc_w   = (const float*)d_in[10];
    const float* fc_b   = (const float*)d_in[11];

    rnn2_fused<<<Bsz / GB, NTHREADS, 0, stream>>>(
        x, hidden, W_ih0, W_hh0, b_ih0, b_hh0,
        W_ih1, W_hh1, b_ih1, b_hh1, fc_w, fc_b, (float*)d_out);
}